// Round 12
// baseline (323.514 us; speedup 1.0000x reference)
//
#include <hip/hip_runtime.h>
#include <stdint.h>

#define B_ 4
#define H_ 16
#define NQ_ 1024
#define NK_ 1024
#define DM_ 1024
#define DK_ 64

typedef __attribute__((ext_vector_type(8))) short short8;
typedef __attribute__((ext_vector_type(4))) float f32x4;
typedef unsigned short u16;
typedef unsigned int u32;

__device__ __forceinline__ u16 f2bf(float f) {
  u32 u = __builtin_bit_cast(u32, f);
  u32 r = u + 0x7fffu + ((u >> 16) & 1u);
  return (u16)(r >> 16);
}

__device__ __forceinline__ float bf2f(u16 b) {
  u32 u = ((u32)b) << 16;
  return __builtin_bit_cast(float, u);
}

__device__ __forceinline__ short8 ld_short8(const u16* p) {
  return __builtin_bit_cast(short8, *(const int4*)p);
}

// ---- asm load primitives: volatile pins issue order; dests forced live ----
__device__ __forceinline__ int4 gload16(const void* p) {
  int4 d;
  asm volatile("global_load_dwordx4 %0, %1, off" : "=v"(d) : "v"(p));
  return d;
}
__device__ __forceinline__ int gload4(const void* p) {
  int d;
  asm volatile("global_load_dword %0, %1, off" : "=v"(d) : "v"(p));
  return d;
}
#define VMW(N) do { asm volatile("s_waitcnt vmcnt(" #N ")" ::: "memory"); \
                    __builtin_amdgcn_sched_barrier(0); } while (0)
#define LGKM_BARRIER() do { \
    asm volatile("s_waitcnt lgkmcnt(0)\n\ts_barrier" ::: "memory"); \
    __builtin_amdgcn_sched_barrier(0); } while (0)

// ---------------------------------------------------------------------------
// Mask storage detector: bool (1 byte/elem) vs int32 (4 bytes/elem).
// ---------------------------------------------------------------------------
__global__ void detect_mask_kernel(const unsigned char* __restrict__ m, int* __restrict__ flag) {
  if (threadIdx.x == 0) {
    int f = 0;
    for (int i = 0; i < 256; ++i)
      if ((i & 3) != 0 && m[i] != 0) f = 1;
    *flag = f;  // 1 => byte mask, 0 => int32 mask
  }
}

// ---------------------------------------------------------------------------
// GEMM v3: 512 threads / 8 waves (2x4), 128x128 tile, BK=32.
// Same math & K-order as v2 (absmax must be bit-identical); only the
// wave->subtile mapping and staging distribution changed (occupancy 2x).
// z==2 writes V k-tiled: vt2[bh][k/32][d][k%32].
// ---------------------------------------------------------------------------
__global__ __launch_bounds__(512) void gemm_kernel(
    const float* __restrict__ Aq, const float* __restrict__ Ak, const float* __restrict__ Av,
    const u16* __restrict__ Ao,
    const float* __restrict__ Wq, const float* __restrict__ Wk,
    const float* __restrict__ Wv, const float* __restrict__ Wo,
    const float* __restrict__ bq, const float* __restrict__ bk,
    const float* __restrict__ bv, const float* __restrict__ bo,
    u16* __restrict__ qbuf, u16* __restrict__ kbuf, u16* __restrict__ vTbuf,
    float* __restrict__ outbuf, int mode_base)
{
  const int z = mode_base + (int)blockIdx.z;
  const int n0 = blockIdx.x * 128;
  const int m0 = blockIdx.y * 128;
  const int tid = threadIdx.x;
  const int lane = tid & 63;
  const int wave = tid >> 6;          // 0..7
  const int wm = wave >> 2, wn = wave & 3;   // 2 x 4
  const int l15 = lane & 15;
  const int hi = lane >> 4;

  __shared__ u16 Al[128 * 40];
  __shared__ u16 Bl[128 * 40];

  const float* Af = (z == 0) ? Aq : (z == 1 ? Ak : Av);
  const float* W  = (z == 0) ? Wq : (z == 1 ? Wk : (z == 2 ? Wv : Wo));

  f32x4 acc[4][2];
#pragma unroll
  for (int i = 0; i < 4; ++i)
#pragma unroll
    for (int j = 0; j < 2; ++j) acc[i][j] = (f32x4){0.f, 0.f, 0.f, 0.f};

  float4 arf[2];
  int4   arb1;
  float4 brf[2];

  auto load_tiles = [&](int ks) {
    const int kk0 = ks * 32;
    if (z < 3) {
#pragma unroll
      for (int c = 0; c < 2; ++c) {
        int chunk = c * 512 + tid;
        arf[c] = *(const float4*)(Af + (size_t)(m0 + (chunk >> 3)) * DM_ + kk0 + (chunk & 7) * 4);
      }
    } else {
      arb1 = *(const int4*)(Ao + (size_t)(m0 + (tid >> 2)) * DM_ + kk0 + (tid & 3) * 8);
    }
#pragma unroll
    for (int c = 0; c < 2; ++c) {
      int chunk = c * 512 + tid;
      brf[c] = *(const float4*)(W + (size_t)(n0 + (chunk >> 3)) * DM_ + kk0 + (chunk & 7) * 4);
    }
  };

  auto store_lds = [&]() {
    if (z < 3) {
#pragma unroll
      for (int c = 0; c < 2; ++c) {
        int chunk = c * 512 + tid;
        ushort4 p;
        p.x = f2bf(arf[c].x); p.y = f2bf(arf[c].y); p.z = f2bf(arf[c].z); p.w = f2bf(arf[c].w);
        *(ushort4*)(Al + (chunk >> 3) * 40 + (chunk & 7) * 4) = p;
      }
    } else {
      *(int4*)(Al + (tid >> 2) * 40 + (tid & 3) * 8) = arb1;
    }
#pragma unroll
    for (int c = 0; c < 2; ++c) {
      int chunk = c * 512 + tid;
      ushort4 p;
      p.x = f2bf(brf[c].x); p.y = f2bf(brf[c].y); p.z = f2bf(brf[c].z); p.w = f2bf(brf[c].w);
      *(ushort4*)(Bl + (chunk >> 3) * 40 + (chunk & 7) * 4) = p;
    }
  };

  load_tiles(0);
  for (int ks = 0; ks < 32; ++ks) {
    __syncthreads();
    store_lds();
    __syncthreads();
    if (ks < 31) load_tiles(ks + 1);
    short8 afr[4], bfr[2];
#pragma unroll
    for (int i = 0; i < 4; ++i)
      afr[i] = ld_short8(Al + (wm * 64 + i * 16 + l15) * 40 + hi * 8);
#pragma unroll
    for (int j = 0; j < 2; ++j)
      bfr[j] = ld_short8(Bl + (wn * 32 + j * 16 + l15) * 40 + hi * 8);
#pragma unroll
    for (int i = 0; i < 4; ++i)
#pragma unroll
      for (int j = 0; j < 2; ++j)
        acc[i][j] = __builtin_amdgcn_mfma_f32_16x16x32_bf16(afr[i], bfr[j], acc[i][j], 0, 0, 0);
  }

  const float* bias = (z == 0) ? bq : (z == 1 ? bk : (z == 2 ? bv : bo));
#pragma unroll
  for (int i = 0; i < 4; ++i) {
    const int token0 = m0 + wm * 64 + i * 16 + hi * 4;
#pragma unroll
    for (int j = 0; j < 2; ++j) {
      const int feat = n0 + wn * 32 + j * 16 + l15;
      const float bvl = bias[feat];
      if (z == 3) {
#pragma unroll
        for (int r = 0; r < 4; ++r)
          outbuf[(size_t)(token0 + r) * DM_ + feat] = acc[i][j][r] + bvl;
      } else if (z == 2) {
        // V k-tiled: vt2[bh][k/32][d][k%32]
        const int bb = token0 >> 10, t = token0 & 1023;
        const int hh = feat >> 6, d = feat & 63;
        const int kt = t >> 5, kk = t & 31;
        ushort4 p;
        p.x = f2bf(acc[i][j][0] + bvl);
        p.y = f2bf(acc[i][j][1] + bvl);
        p.z = f2bf(acc[i][j][2] + bvl);
        p.w = f2bf(acc[i][j][3] + bvl);
        *(ushort4*)(vTbuf + (((size_t)(bb * H_ + hh) * 32 + kt) * 64 + d) * 32 + kk) = p;
      } else {
        u16* dst = (z == 0) ? qbuf : kbuf;
        const int hh = feat >> 6, d = feat & 63;
#pragma unroll
        for (int r = 0; r < 4; ++r) {
          const int token = token0 + r;
          const int bb = token >> 10, t = token & 1023;
          dst[((size_t)(bb * H_ + hh) * NQ_ + t) * DK_ + d] = f2bf(acc[i][j][r] + bvl);
        }
      }
    }
  }
}

// ---------------------------------------------------------------------------
// Attention v10 (R11) + __launch_bounds__(512,4) occupancy hint.
// ---------------------------------------------------------------------------
__global__ __launch_bounds__(512, 4) void attn_kernel(
    const u16* __restrict__ qbuf, const u16* __restrict__ kbuf, const u16* __restrict__ vTbuf,
    const float* __restrict__ aw, const void* __restrict__ maskp, const int* __restrict__ flagp,
    float* __restrict__ attout, u16* __restrict__ obuf)
{
  __shared__ u16 S[16 * 1024];  // 32 KB bf16 strip, col swizzle: c ^ ((row&7)<<3)

  const int n = blockIdx.x;
  const int work = (n & 7) * 512 + (n >> 3);  // XCD-chunked swizzle (perf only)
  const int qt = work & 63;
  const int bh = work >> 6;
  const int b = bh >> 4, h = bh & 15;
  const int qbase = qt * 16;
  const int tid = threadIdx.x;
  const int lane = tid & 63;
  const int wave = tid >> 6;   // 0..7
  const int hi = lane >> 4;
  const int l15 = lane & 15;
  const int l4 = lane * 4;
  const int mflag = *flagp;

  const size_t ab0 = ((size_t)bh * NQ_ + qbase + wave) * (size_t)NK_;
  const size_t ab1 = ab0 + 8 * (size_t)NK_;

  // ---- pre-QK issue: Q(2), K(16), aw row0(4) -- FIFO order is the contract
  const u16* qp = qbuf + ((size_t)bh * NQ_ + qbase + l15) * DK_ + hi * 8;
  int4 qd0 = gload16(qp);
  int4 qd1 = gload16(qp + 32);

  const u16* kbase = kbuf + (size_t)bh * NK_ * DK_;
  const int tkc = wave * 16 + l15;
  int4 kq0[8], kq1[8];
#pragma unroll
  for (int t = 0; t < 8; ++t) {
    const u16* kp_ = kbase + (size_t)(t * 128 + tkc) * DK_ + hi * 8;
    kq0[t] = gload16(kp_);
    kq1[t] = gload16(kp_ + 32);
  }
  int4 aw0[4];
#pragma unroll
  for (int j = 0; j < 4; ++j) aw0[j] = gload16(aw + ab0 + l4 + j * 256);
  // outstanding: 22.  oldest->newest: Q(2), K(16), awR0(4)

  VMW(20);  // Q ready
  const short8 qf0 = __builtin_bit_cast(short8, qd0);
  const short8 qf1 = __builtin_bit_cast(short8, qd1);

#define QK_EAT(t) do { \
    f32x4 sacc_ = (f32x4){0.f, 0.f, 0.f, 0.f}; \
    sacc_ = __builtin_amdgcn_mfma_f32_16x16x32_bf16(qf0, __builtin_bit_cast(short8, kq0[t]), sacc_, 0, 0, 0); \
    sacc_ = __builtin_amdgcn_mfma_f32_16x16x32_bf16(qf1, __builtin_bit_cast(short8, kq1[t]), sacc_, 0, 0, 0); \
    const int tk_ = (t) * 128 + tkc; \
    _Pragma("unroll") \
    for (int r = 0; r < 4; ++r) { \
      const int row_ = hi * 4 + r; \
      S[row_ * 1024 + (tk_ ^ ((row_ & 7) << 3))] = f2bf(sacc_[r]); \
    } } while (0)

  VMW(16);  QK_EAT(0); QK_EAT(1);
  VMW(12);  QK_EAT(2); QK_EAT(3);
  VMW(8);   QK_EAT(4); QK_EAT(5);
  VMW(4);   QK_EAT(6); QK_EAT(7);   // awR0(4) still in flight
#undef QK_EAT

  LGKM_BARRIER();   // S strip visible; aw loads NOT drained

  // ---- softmax (no max-sub): rows wave, wave+8; contiguous access ----
  {
    const float scale = 0.125f;

#define SM_BODY(row_, AWV_, KV_, ab_) do { \
    u16* Srow_ = S + (row_) * 1024; \
    const int swz_ = ((row_) & 7) << 3; \
    f32x4 e_[4]; float sum_ = 0.f; \
    _Pragma("unroll") \
    for (int j = 0; j < 4; ++j) { \
      const int c_ = l4 + j * 256; \
      const ushort4 s4_ = *(const ushort4*)(Srow_ + (c_ ^ swz_)); \
      const f32x4 a4_ = __builtin_bit_cast(f32x4, AWV_[j]); \
      f32x4 t_; \
      t_[0] = KV_[j].x ? 0.f : __expf(bf2f(s4_.x) * scale * a4_[0]); \
      t_[1] = KV_[j].y ? 0.f : __expf(bf2f(s4_.y) * scale * a4_[1]); \
      t_[2] = KV_[j].z ? 0.f : __expf(bf2f(s4_.z) * scale * a4_[2]); \
      t_[3] = KV_[j].w ? 0.f : __expf(bf2f(s4_.w) * scale * a4_[3]); \
      e_[j] = t_; \
      sum_ += (t_[0] + t_[1]) + (t_[2] + t_[3]); \
    } \
    _Pragma("unroll") \
    for (int o_ = 32; o_ >= 1; o_ >>= 1) sum_ += __shfl_xor(sum_, o_); \
    const float inv_ = 1.0f / sum_; \
    _Pragma("unroll") \
    for (int j = 0; j < 4; ++j) { \
      const int c_ = l4 + j * 256; \
      f32x4 t_ = e_[j]; \
      t_[0] *= inv_; t_[1] *= inv_; t_[2] *= inv_; t_[3] *= inv_; \
      *(f32x4*)(attout + (ab_) + c_) = t_; \
      ushort4 p_; \
      p_.x = f2bf(t_[0]); p_.y = f2bf(t_[1]); p_.z = f2bf(t_[2]); p_.w = f2bf(t_[3]); \
      *(ushort4*)(Srow_ + (c_ ^ swz_)) = p_; \
    } \
  } while (0)

    if (mflag) {
      const unsigned char* mp = (const unsigned char*)maskp;
      int mb0[4], mb1[4];
      int4 aw1[4];
#pragma unroll
      for (int j = 0; j < 4; ++j) mb0[j] = gload4(mp + ab0 + l4 + j * 256);
#pragma unroll
      for (int j = 0; j < 4; ++j) aw1[j] = gload16(aw + ab1 + l4 + j * 256);
#pragma unroll
      for (int j = 0; j < 4; ++j) mb1[j] = gload4(mp + ab1 + l4 + j * 256);
      VMW(8);  // awR0 + maskR0 ready; row1's 8 in flight
      int4 k0[4], k1[4];
#pragma unroll
      for (int j = 0; j < 4; ++j) {
        k0[j].x = mb0[j] & 0xff;          k0[j].y = (mb0[j] >> 8) & 0xff;
        k0[j].z = (mb0[j] >> 16) & 0xff;  k0[j].w = (mb0[j] >> 24) & 0xff;
      }
      SM_BODY(wave, aw0, k0, ab0);
      VMW(4);  // awR1 + maskR1 ready; row0's 4 attout stores remain
#pragma unroll
      for (int j = 0; j < 4; ++j) {
        k1[j].x = mb1[j] & 0xff;          k1[j].y = (mb1[j] >> 8) & 0xff;
        k1[j].z = (mb1[j] >> 16) & 0xff;  k1[j].w = (mb1[j] >> 24) & 0xff;
      }
      SM_BODY(wave + 8, aw1, k1, ab1);
    } else {
      const int* mp = (const int*)maskp;
      int4 k0[4], aw1[4], k1[4];
#pragma unroll
      for (int j = 0; j < 4; ++j) k0[j] = gload16(mp + ab0 + l4 + j * 256);
#pragma unroll
      for (int j = 0; j < 4; ++j) aw1[j] = gload16(aw + ab1 + l4 + j * 256);
#pragma unroll
      for (int j = 0; j < 4; ++j) k1[j] = gload16(mp + ab1 + l4 + j * 256);
      VMW(8);  // awR0 + maskR0 ready
      SM_BODY(wave, aw0, k0, ab0);
      VMW(4);  // row1 loads ready; row0 stores remain
      SM_BODY(wave + 8, aw1, k1, ab1);
    }
#undef SM_BODY
  }

  LGKM_BARRIER();  // P strip visible for PV; attout stores still in flight
  VMW(0);          // clean FIFO before PV's counted pipeline

  // ---- PV: 2-way k-split, k-tiled V (contiguous loads), dual accumulators
  {
    const int kh = wave >> 2;
    const int j = wave & 3;
    const u16* Sr = S + l15 * 1024;
    const int asw = (l15 & 7) << 3;
    const int dcol = j * 16 + l15;
    const u16* vb2 = vTbuf + (size_t)bh * (NK_ * DK_);
    const int kh512 = kh * 512;
    f32x4 o0 = (f32x4){0.f, 0.f, 0.f, 0.f};
    f32x4 o1 = (f32x4){0.f, 0.f, 0.f, 0.f};
    int4 vq[16];

#define PV_ISSUE(t) do { \
    vq[t] = gload16(vb2 + ((size_t)(kh * 16 + (t)) * 64 + dcol) * 32 + hi * 8); } while (0)
#define PV_EAT(t) do { \
    const int c_ = kh512 + (t) * 32 + hi * 8; \
    const short8 pa_ = ld_short8(Sr + (c_ ^ asw)); \
    if ((t) & 1) o1 = __builtin_amdgcn_mfma_f32_16x16x32_bf16(pa_, __builtin_bit_cast(short8, vq[t]), o1, 0, 0, 0); \
    else        o0 = __builtin_amdgcn_mfma_f32_16x16x32_bf16(pa_, __builtin_bit_cast(short8, vq[t]), o0, 0, 0, 0); \
  } while (0)

    PV_ISSUE(0); PV_ISSUE(1); PV_ISSUE(2); PV_ISSUE(3);
    PV_ISSUE(4); PV_ISSUE(5); PV_ISSUE(6); PV_ISSUE(7);
    VMW(4);
    PV_EAT(0); PV_EAT(1); PV_EAT(2); PV_EAT(3);
    PV_ISSUE(8); PV_ISSUE(9); PV_ISSUE(10); PV_ISSUE(11);
    VMW(4);
    PV_EAT(4); PV_EAT(5); PV_EAT(6); PV_EAT(7);
    PV_ISSUE(12); PV_ISSUE(13); PV_ISSUE(14); PV_ISSUE(15);
    VMW(4);
    PV_EAT(8); PV_EAT(9); PV_EAT(10); PV_EAT(11);
    VMW(0);
    PV_EAT(12); PV_EAT(13); PV_EAT(14); PV_EAT(15);
#undef PV_ISSUE
#undef PV_EAT

    f32x4 oacc = o0 + o1;
    __syncthreads();                 // all P strip reads complete
    float* Pbuf = (float*)S;         // 16 x 64 fp32 partials (4 KB, aliases S)
    if (kh == 1) {
#pragma unroll
      for (int r = 0; r < 4; ++r)
        Pbuf[(hi * 4 + r) * 64 + dcol] = oacc[r];
    }
    __syncthreads();
    if (kh == 0) {
      const int feat = h * DK_ + dcol;
#pragma unroll
      for (int r = 0; r < 4; ++r) {
        const int row = hi * 4 + r;
        obuf[((size_t)b * NQ_ + qbase + row) * DM_ + feat] =
            f2bf(oacc[r] + Pbuf[row * 64 + dcol]);
      }
    }
  }
}

// ---------------------------------------------------------------------------
extern "C" void kernel_launch(void* const* d_in, const int* in_sizes, int n_in,
                              void* d_out, int out_size, void* d_ws, size_t ws_size,
                              hipStream_t stream)
{
  const float* queries = (const float*)d_in[0];
  const float* keys    = (const float*)d_in[1];
  const float* values  = (const float*)d_in[2];
  const float* aw      = (const float*)d_in[3];
  const void*  maskp   = d_in[4];
  const float* Wq = (const float*)d_in[5];
  const float* bq = (const float*)d_in[6];
  const float* Wk = (const float*)d_in[7];
  const float* bk = (const float*)d_in[8];
  const float* Wv = (const float*)d_in[9];
  const float* bv = (const float*)d_in[10];
  const float* Wo = (const float*)d_in[11];
  const float* bo = (const float*)d_in[12];

  char* ws = (char*)d_ws;
  const size_t NE = (size_t)B_ * H_ * NQ_ * DK_;
  int* flag  = (int*)ws;
  u16* qbuf  = (u16*)(ws + 256);
  u16* kbuf  = qbuf + NE;
  u16* vTbuf = kbuf + NE;
  u16* obuf  = vTbuf + NE;
  if (ws_size < 256 + 8 * NE) return;

  float* outp = (float*)d_out;
  float* attp = outp + (size_t)B_ * NQ_ * DM_;

  detect_mask_kernel<<<1, 64, 0, stream>>>((const unsigned char*)maskp, flag);

  gemm_kernel<<<dim3(8, 32, 3), 512, 0, stream>>>(queries, keys, values, obuf,
      Wq, Wk, Wv, Wo, bq, bk, bv, bo, qbuf, kbuf, vTbuf, outp, 0);

  attn_kernel<<<dim3(4096), 512, 0, stream>>>(qbuf, kbuf, vTbuf, aw, maskp, flag,
                                              attp, obuf);

  gemm_kernel<<<dim3(8, 32, 1), 512, 0, stream>>>(queries, keys, values, obuf,
      Wq, Wk, Wv, Wo, bq, bk, bv, bo, qbuf, kbuf, vTbuf, outp, 3);
}

// Round 14
// 290.601 us; speedup vs baseline: 1.1133x; 1.1133x over previous
//
#include <hip/hip_runtime.h>
#include <stdint.h>

#define B_ 4
#define H_ 16
#define NQ_ 1024
#define NK_ 1024
#define DM_ 1024
#define DK_ 64

typedef __attribute__((ext_vector_type(8))) short short8;
typedef __attribute__((ext_vector_type(4))) float f32x4;
typedef __attribute__((ext_vector_type(4))) int i32x4;
typedef unsigned short u16;
typedef unsigned int u32;

__device__ __forceinline__ u16 f2bf(float f) {
  u32 u = __builtin_bit_cast(u32, f);
  u32 r = u + 0x7fffu + ((u >> 16) & 1u);
  return (u16)(r >> 16);
}

__device__ __forceinline__ float bf2f(u16 b) {
  u32 u = ((u32)b) << 16;
  return __builtin_bit_cast(float, u);
}

__device__ __forceinline__ short8 ld_short8(const u16* p) {
  return __builtin_bit_cast(short8, *(const int4*)p);
}

// ---- asm load/store primitives ----
__device__ __forceinline__ int4 gload16(const void* p) {
  int4 d;
  asm volatile("global_load_dwordx4 %0, %1, off" : "=v"(d) : "v"(p));
  return d;
}
__device__ __forceinline__ int4 gload16_nt(const void* p) {
  int4 d;
  asm volatile("global_load_dwordx4 %0, %1, off nt" : "=v"(d) : "v"(p));
  return d;
}
__device__ __forceinline__ int gload4_nt(const void* p) {
  int d;
  asm volatile("global_load_dword %0, %1, off nt" : "=v"(d) : "v"(p));
  return d;
}
// NOTE: input operand must be a native ext_vector (i32x4), NOT HIP's int4
// struct -- LLVM cannot pass struct-typed (indirect) values to "v" inputs.
__device__ __forceinline__ void gstore16_nt(void* p, i32x4 v) {
  asm volatile("global_store_dwordx4 %0, %1, off nt" :: "v"(p), "v"(v) : "memory");
}
#define VMW(N) do { asm volatile("s_waitcnt vmcnt(" #N ")" ::: "memory"); \
                    __builtin_amdgcn_sched_barrier(0); } while (0)
#define LGKM_BARRIER() do { \
    asm volatile("s_waitcnt lgkmcnt(0)\n\ts_barrier" ::: "memory"); \
    __builtin_amdgcn_sched_barrier(0); } while (0)

// ---------------------------------------------------------------------------
// Mask storage detector: bool (1 byte/elem) vs int32 (4 bytes/elem).
// ---------------------------------------------------------------------------
__global__ void detect_mask_kernel(const unsigned char* __restrict__ m, int* __restrict__ flag) {
  if (threadIdx.x == 0) {
    int f = 0;
    for (int i = 0; i < 256; ++i)
      if ((i & 3) != 0 && m[i] != 0) f = 1;
    *flag = f;  // 1 => byte mask, 0 => int32 mask
  }
}

// ---------------------------------------------------------------------------
// GEMM v2 (R11, best known): 256 thr / 4 waves, 128x128 tile, BK=32.
// z==2 writes V k-tiled: vt2[bh][k/32][d][k%32].
// ---------------------------------------------------------------------------
__global__ __launch_bounds__(256) void gemm_kernel(
    const float* __restrict__ Aq, const float* __restrict__ Ak, const float* __restrict__ Av,
    const u16* __restrict__ Ao,
    const float* __restrict__ Wq, const float* __restrict__ Wk,
    const float* __restrict__ Wv, const float* __restrict__ Wo,
    const float* __restrict__ bq, const float* __restrict__ bk,
    const float* __restrict__ bv, const float* __restrict__ bo,
    u16* __restrict__ qbuf, u16* __restrict__ kbuf, u16* __restrict__ vTbuf,
    float* __restrict__ outbuf, int mode_base)
{
  const int z = mode_base + (int)blockIdx.z;
  const int n0 = blockIdx.x * 128;
  const int m0 = blockIdx.y * 128;
  const int tid = threadIdx.x;
  const int lane = tid & 63;
  const int wave = tid >> 6;
  const int wm = wave >> 1, wn = wave & 1;

  __shared__ u16 Al[128 * 40];
  __shared__ u16 Bl[128 * 40];

  const float* Af = (z == 0) ? Aq : (z == 1 ? Ak : Av);
  const float* W  = (z == 0) ? Wq : (z == 1 ? Wk : (z == 2 ? Wv : Wo));

  f32x4 acc[4][4];
#pragma unroll
  for (int i = 0; i < 4; ++i)
#pragma unroll
    for (int j = 0; j < 4; ++j) acc[i][j] = (f32x4){0.f, 0.f, 0.f, 0.f};

  float4 arf[4];
  int4   arb[2];
  float4 brf[4];

  auto load_tiles = [&](int ks) {
    const int kk0 = ks * 32;
    if (z < 3) {
#pragma unroll
      for (int c = 0; c < 4; ++c) {
        int chunk = c * 256 + tid;
        arf[c] = *(const float4*)(Af + (size_t)(m0 + (chunk >> 3)) * DM_ + kk0 + (chunk & 7) * 4);
      }
    } else {
#pragma unroll
      for (int c = 0; c < 2; ++c) {
        int chunk = c * 256 + tid;
        arb[c] = *(const int4*)(Ao + (size_t)(m0 + (chunk >> 2)) * DM_ + kk0 + (chunk & 3) * 8);
      }
    }
#pragma unroll
    for (int c = 0; c < 4; ++c) {
      int chunk = c * 256 + tid;
      brf[c] = *(const float4*)(W + (size_t)(n0 + (chunk >> 3)) * DM_ + kk0 + (chunk & 7) * 4);
    }
  };

  auto store_lds = [&]() {
    if (z < 3) {
#pragma unroll
      for (int c = 0; c < 4; ++c) {
        int chunk = c * 256 + tid;
        ushort4 p;
        p.x = f2bf(arf[c].x); p.y = f2bf(arf[c].y); p.z = f2bf(arf[c].z); p.w = f2bf(arf[c].w);
        *(ushort4*)(Al + (chunk >> 3) * 40 + (chunk & 7) * 4) = p;
      }
    } else {
#pragma unroll
      for (int c = 0; c < 2; ++c) {
        int chunk = c * 256 + tid;
        *(int4*)(Al + (chunk >> 2) * 40 + (chunk & 3) * 8) = arb[c];
      }
    }
#pragma unroll
    for (int c = 0; c < 4; ++c) {
      int chunk = c * 256 + tid;
      ushort4 p;
      p.x = f2bf(brf[c].x); p.y = f2bf(brf[c].y); p.z = f2bf(brf[c].z); p.w = f2bf(brf[c].w);
      *(ushort4*)(Bl + (chunk >> 3) * 40 + (chunk & 7) * 4) = p;
    }
  };

  load_tiles(0);
  for (int ks = 0; ks < 32; ++ks) {
    __syncthreads();
    store_lds();
    __syncthreads();
    if (ks < 31) load_tiles(ks + 1);
    short8 afr[4], bfr[4];
#pragma unroll
    for (int i = 0; i < 4; ++i) {
      afr[i] = ld_short8(Al + (wm * 64 + i * 16 + (lane & 15)) * 40 + (lane >> 4) * 8);
      bfr[i] = ld_short8(Bl + (wn * 64 + i * 16 + (lane & 15)) * 40 + (lane >> 4) * 8);
    }
#pragma unroll
    for (int i = 0; i < 4; ++i)
#pragma unroll
      for (int j = 0; j < 4; ++j)
        acc[i][j] = __builtin_amdgcn_mfma_f32_16x16x32_bf16(afr[i], bfr[j], acc[i][j], 0, 0, 0);
  }

  const float* bias = (z == 0) ? bq : (z == 1 ? bk : (z == 2 ? bv : bo));
#pragma unroll
  for (int i = 0; i < 4; ++i) {
    const int token0 = m0 + wm * 64 + i * 16 + (lane >> 4) * 4;
#pragma unroll
    for (int j = 0; j < 4; ++j) {
      const int feat = n0 + wn * 64 + j * 16 + (lane & 15);
      const float bvl = bias[feat];
      if (z == 3) {
#pragma unroll
        for (int r = 0; r < 4; ++r)
          outbuf[(size_t)(token0 + r) * DM_ + feat] = acc[i][j][r] + bvl;
      } else if (z == 2) {
        // V k-tiled: vt2[bh][k/32][d][k%32]
        const int bb = token0 >> 10, t = token0 & 1023;
        const int hh = feat >> 6, d = feat & 63;
        const int kt = t >> 5, kk = t & 31;
        ushort4 p;
        p.x = f2bf(acc[i][j][0] + bvl);
        p.y = f2bf(acc[i][j][1] + bvl);
        p.z = f2bf(acc[i][j][2] + bvl);
        p.w = f2bf(acc[i][j][3] + bvl);
        *(ushort4*)(vTbuf + (((size_t)(bb * H_ + hh) * 32 + kt) * 64 + d) * 32 + kk) = p;
      } else {
        u16* dst = (z == 0) ? qbuf : kbuf;
        const int hh = feat >> 6, d = feat & 63;
#pragma unroll
        for (int r = 0; r < 4; ++r) {
          const int token = token0 + r;
          const int bb = token >> 10, t = token & 1023;
          dst[((size_t)(bb * H_ + hh) * NQ_ + t) * DK_ + d] = f2bf(acc[i][j][r] + bvl);
        }
      }
    }
  }
}

// ---------------------------------------------------------------------------
// Attention v11: R11 structure + NON-TEMPORAL hints on the stream traffic
// (aw loads, mask loads, attout stores) so K/V/Q stay L2-resident.
// ---------------------------------------------------------------------------
__global__ __launch_bounds__(512) void attn_kernel(
    const u16* __restrict__ qbuf, const u16* __restrict__ kbuf, const u16* __restrict__ vTbuf,
    const float* __restrict__ aw, const void* __restrict__ maskp, const int* __restrict__ flagp,
    float* __restrict__ attout, u16* __restrict__ obuf)
{
  __shared__ u16 S[16 * 1024];  // 32 KB bf16 strip, col swizzle: c ^ ((row&7)<<3)

  const int n = blockIdx.x;
  const int work = (n & 7) * 512 + (n >> 3);  // XCD-chunked swizzle (perf only)
  const int qt = work & 63;
  const int bh = work >> 6;
  const int b = bh >> 4, h = bh & 15;
  const int qbase = qt * 16;
  const int tid = threadIdx.x;
  const int lane = tid & 63;
  const int wave = tid >> 6;   // 0..7
  const int hi = lane >> 4;
  const int l15 = lane & 15;
  const int l4 = lane * 4;
  const int mflag = *flagp;

  const size_t ab0 = ((size_t)bh * NQ_ + qbase + wave) * (size_t)NK_;
  const size_t ab1 = ab0 + 8 * (size_t)NK_;

  // ---- pre-QK issue: Q(2), K(16), aw row0(4) -- FIFO order is the contract
  const u16* qp = qbuf + ((size_t)bh * NQ_ + qbase + l15) * DK_ + hi * 8;
  int4 qd0 = gload16(qp);
  int4 qd1 = gload16(qp + 32);

  const u16* kbase = kbuf + (size_t)bh * NK_ * DK_;
  const int tkc = wave * 16 + l15;
  int4 kq0[8], kq1[8];
#pragma unroll
  for (int t = 0; t < 8; ++t) {
    const u16* kp_ = kbase + (size_t)(t * 128 + tkc) * DK_ + hi * 8;
    kq0[t] = gload16(kp_);
    kq1[t] = gload16(kp_ + 32);
  }
  int4 aw0[4];
#pragma unroll
  for (int j = 0; j < 4; ++j) aw0[j] = gload16_nt(aw + ab0 + l4 + j * 256);
  // outstanding: 22.  oldest->newest: Q(2), K(16), awR0(4)

  VMW(20);  // Q ready
  const short8 qf0 = __builtin_bit_cast(short8, qd0);
  const short8 qf1 = __builtin_bit_cast(short8, qd1);

#define QK_EAT(t) do { \
    f32x4 sacc_ = (f32x4){0.f, 0.f, 0.f, 0.f}; \
    sacc_ = __builtin_amdgcn_mfma_f32_16x16x32_bf16(qf0, __builtin_bit_cast(short8, kq0[t]), sacc_, 0, 0, 0); \
    sacc_ = __builtin_amdgcn_mfma_f32_16x16x32_bf16(qf1, __builtin_bit_cast(short8, kq1[t]), sacc_, 0, 0, 0); \
    const int tk_ = (t) * 128 + tkc; \
    _Pragma("unroll") \
    for (int r = 0; r < 4; ++r) { \
      const int row_ = hi * 4 + r; \
      S[row_ * 1024 + (tk_ ^ ((row_ & 7) << 3))] = f2bf(sacc_[r]); \
    } } while (0)

  VMW(16);  QK_EAT(0); QK_EAT(1);
  VMW(12);  QK_EAT(2); QK_EAT(3);
  VMW(8);   QK_EAT(4); QK_EAT(5);
  VMW(4);   QK_EAT(6); QK_EAT(7);   // awR0(4) still in flight
#undef QK_EAT

  LGKM_BARRIER();   // S strip visible; aw loads NOT drained

  // ---- softmax (no max-sub): rows wave, wave+8; contiguous NT access ----
  {
    const float scale = 0.125f;

#define SM_BODY(row_, AWV_, KV_, ab_) do { \
    u16* Srow_ = S + (row_) * 1024; \
    const int swz_ = ((row_) & 7) << 3; \
    f32x4 e_[4]; float sum_ = 0.f; \
    _Pragma("unroll") \
    for (int j = 0; j < 4; ++j) { \
      const int c_ = l4 + j * 256; \
      const ushort4 s4_ = *(const ushort4*)(Srow_ + (c_ ^ swz_)); \
      const f32x4 a4_ = __builtin_bit_cast(f32x4, AWV_[j]); \
      f32x4 t_; \
      t_[0] = KV_[j].x ? 0.f : __expf(bf2f(s4_.x) * scale * a4_[0]); \
      t_[1] = KV_[j].y ? 0.f : __expf(bf2f(s4_.y) * scale * a4_[1]); \
      t_[2] = KV_[j].z ? 0.f : __expf(bf2f(s4_.z) * scale * a4_[2]); \
      t_[3] = KV_[j].w ? 0.f : __expf(bf2f(s4_.w) * scale * a4_[3]); \
      e_[j] = t_; \
      sum_ += (t_[0] + t_[1]) + (t_[2] + t_[3]); \
    } \
    _Pragma("unroll") \
    for (int o_ = 32; o_ >= 1; o_ >>= 1) sum_ += __shfl_xor(sum_, o_); \
    const float inv_ = 1.0f / sum_; \
    _Pragma("unroll") \
    for (int j = 0; j < 4; ++j) { \
      const int c_ = l4 + j * 256; \
      f32x4 t_ = e_[j]; \
      t_[0] *= inv_; t_[1] *= inv_; t_[2] *= inv_; t_[3] *= inv_; \
      gstore16_nt((void*)(attout + (ab_) + c_), __builtin_bit_cast(i32x4, t_)); \
      ushort4 p_; \
      p_.x = f2bf(t_[0]); p_.y = f2bf(t_[1]); p_.z = f2bf(t_[2]); p_.w = f2bf(t_[3]); \
      *(ushort4*)(Srow_ + (c_ ^ swz_)) = p_; \
    } \
  } while (0)

    if (mflag) {
      const unsigned char* mp = (const unsigned char*)maskp;
      int mb0[4], mb1[4];
      int4 aw1[4];
#pragma unroll
      for (int j = 0; j < 4; ++j) mb0[j] = gload4_nt(mp + ab0 + l4 + j * 256);
#pragma unroll
      for (int j = 0; j < 4; ++j) aw1[j] = gload16_nt(aw + ab1 + l4 + j * 256);
#pragma unroll
      for (int j = 0; j < 4; ++j) mb1[j] = gload4_nt(mp + ab1 + l4 + j * 256);
      VMW(8);  // awR0 + maskR0 ready; row1's 8 in flight
      int4 k0[4], k1[4];
#pragma unroll
      for (int j = 0; j < 4; ++j) {
        k0[j].x = mb0[j] & 0xff;          k0[j].y = (mb0[j] >> 8) & 0xff;
        k0[j].z = (mb0[j] >> 16) & 0xff;  k0[j].w = (mb0[j] >> 24) & 0xff;
      }
      SM_BODY(wave, aw0, k0, ab0);
      VMW(4);  // awR1 + maskR1 ready; row0's 4 nt-stores are the newest 4
#pragma unroll
      for (int j = 0; j < 4; ++j) {
        k1[j].x = mb1[j] & 0xff;          k1[j].y = (mb1[j] >> 8) & 0xff;
        k1[j].z = (mb1[j] >> 16) & 0xff;  k1[j].w = (mb1[j] >> 24) & 0xff;
      }
      SM_BODY(wave + 8, aw1, k1, ab1);
    } else {
      const int* mp = (const int*)maskp;
      int4 k0[4], aw1[4], k1[4];
#pragma unroll
      for (int j = 0; j < 4; ++j) k0[j] = gload16_nt(mp + ab0 + l4 + j * 256);
#pragma unroll
      for (int j = 0; j < 4; ++j) aw1[j] = gload16_nt(aw + ab1 + l4 + j * 256);
#pragma unroll
      for (int j = 0; j < 4; ++j) k1[j] = gload16_nt(mp + ab1 + l4 + j * 256);
      VMW(8);  // awR0 + maskR0 ready
      SM_BODY(wave, aw0, k0, ab0);
      VMW(4);  // row1 loads ready; row0 nt-stores remain
      SM_BODY(wave + 8, aw1, k1, ab1);
    }
#undef SM_BODY
  }

  LGKM_BARRIER();  // P strip visible for PV; attout stores still in flight
  VMW(0);          // clean FIFO before PV's counted pipeline

  // ---- PV: 2-way k-split, k-tiled V (contiguous loads), dual accumulators
  {
    const int kh = wave >> 2;
    const int j = wave & 3;
    const u16* Sr = S + l15 * 1024;
    const int asw = (l15 & 7) << 3;
    const int dcol = j * 16 + l15;
    const u16* vb2 = vTbuf + (size_t)bh * (NK_ * DK_);
    const int kh512 = kh * 512;
    f32x4 o0 = (f32x4){0.f, 0.f, 0.f, 0.f};
    f32x4 o1 = (f32x4){0.f, 0.f, 0.f, 0.f};
    int4 vq[16];

#define PV_ISSUE(t) do { \
    vq[t] = gload16(vb2 + ((size_t)(kh * 16 + (t)) * 64 + dcol) * 32 + hi * 8); } while (0)
#define PV_EAT(t) do { \
    const int c_ = kh512 + (t) * 32 + hi * 8; \
    const short8 pa_ = ld_short8(Sr + (c_ ^ asw)); \
    if ((t) & 1) o1 = __builtin_amdgcn_mfma_f32_16x16x32_bf16(pa_, __builtin_bit_cast(short8, vq[t]), o1, 0, 0, 0); \
    else        o0 = __builtin_amdgcn_mfma_f32_16x16x32_bf16(pa_, __builtin_bit_cast(short8, vq[t]), o0, 0, 0, 0); \
  } while (0)

    PV_ISSUE(0); PV_ISSUE(1); PV_ISSUE(2); PV_ISSUE(3);
    PV_ISSUE(4); PV_ISSUE(5); PV_ISSUE(6); PV_ISSUE(7);
    VMW(4);
    PV_EAT(0); PV_EAT(1); PV_EAT(2); PV_EAT(3);
    PV_ISSUE(8); PV_ISSUE(9); PV_ISSUE(10); PV_ISSUE(11);
    VMW(4);
    PV_EAT(4); PV_EAT(5); PV_EAT(6); PV_EAT(7);
    PV_ISSUE(12); PV_ISSUE(13); PV_ISSUE(14); PV_ISSUE(15);
    VMW(4);
    PV_EAT(8); PV_EAT(9); PV_EAT(10); PV_EAT(11);
    VMW(0);
    PV_EAT(12); PV_EAT(13); PV_EAT(14); PV_EAT(15);
#undef PV_ISSUE
#undef PV_EAT

    f32x4 oacc = o0 + o1;
    __syncthreads();                 // all P strip reads complete
    float* Pbuf = (float*)S;         // 16 x 64 fp32 partials (4 KB, aliases S)
    if (kh == 1) {
#pragma unroll
      for (int r = 0; r < 4; ++r)
        Pbuf[(hi * 4 + r) * 64 + dcol] = oacc[r];
    }
    __syncthreads();
    if (kh == 0) {
      const int feat = h * DK_ + dcol;
#pragma unroll
      for (int r = 0; r < 4; ++r) {
        const int row = hi * 4 + r;
        obuf[((size_t)b * NQ_ + qbase + row) * DM_ + feat] =
            f2bf(oacc[r] + Pbuf[row * 64 + dcol]);
      }
    }
  }
}

// ---------------------------------------------------------------------------
extern "C" void kernel_launch(void* const* d_in, const int* in_sizes, int n_in,
                              void* d_out, int out_size, void* d_ws, size_t ws_size,
                              hipStream_t stream)
{
  const float* queries = (const float*)d_in[0];
  const float* keys    = (const float*)d_in[1];
  const float* values  = (const float*)d_in[2];
  const float* aw      = (const float*)d_in[3];
  const void*  maskp   = d_in[4];
  const float* Wq = (const float*)d_in[5];
  const float* bq = (const float*)d_in[6];
  const float* Wk = (const float*)d_in[7];
  const float* bk = (const float*)d_in[8];
  const float* Wv = (const float*)d_in[9];
  const float* bv = (const float*)d_in[10];
  const float* Wo = (const float*)d_in[11];
  const float* bo = (const float*)d_in[12];

  char* ws = (char*)d_ws;
  const size_t NE = (size_t)B_ * H_ * NQ_ * DK_;
  int* flag  = (int*)ws;
  u16* qbuf  = (u16*)(ws + 256);
  u16* kbuf  = qbuf + NE;
  u16* vTbuf = kbuf + NE;
  u16* obuf  = vTbuf + NE;
  if (ws_size < 256 + 8 * NE) return;

  float* outp = (float*)d_out;
  float* attp = outp + (size_t)B_ * NQ_ * DM_;

  detect_mask_kernel<<<1, 64, 0, stream>>>((const unsigned char*)maskp, flag);

  gemm_kernel<<<dim3(8, 32, 3), 256, 0, stream>>>(queries, keys, values, obuf,
      Wq, Wk, Wv, Wo, bq, bk, bv, bo, qbuf, kbuf, vTbuf, outp, 0);

  attn_kernel<<<dim3(4096), 512, 0, stream>>>(qbuf, kbuf, vTbuf, aw, maskp, flag,
                                              attp, obuf);

  gemm_kernel<<<dim3(8, 32, 1), 256, 0, stream>>>(queries, keys, values, obuf,
      Wq, Wk, Wv, Wo, bq, bk, bv, bo, qbuf, kbuf, vTbuf, outp, 3);
}

// Round 15
// 290.220 us; speedup vs baseline: 1.1147x; 1.0013x over previous
//
#include <hip/hip_runtime.h>
#include <stdint.h>

#define B_ 4
#define H_ 16
#define NQ_ 1024
#define NK_ 1024
#define DM_ 1024
#define DK_ 64

typedef __attribute__((ext_vector_type(8))) short short8;
typedef __attribute__((ext_vector_type(4))) float f32x4;
typedef __attribute__((ext_vector_type(4))) int i32x4;
typedef unsigned short u16;
typedef unsigned int u32;

__device__ __forceinline__ u16 f2bf(float f) {
  u32 u = __builtin_bit_cast(u32, f);
  u32 r = u + 0x7fffu + ((u >> 16) & 1u);
  return (u16)(r >> 16);
}

__device__ __forceinline__ float bf2f(u16 b) {
  u32 u = ((u32)b) << 16;
  return __builtin_bit_cast(float, u);
}

__device__ __forceinline__ short8 ld_short8(const u16* p) {
  return __builtin_bit_cast(short8, *(const int4*)p);
}

// ---- asm load/store primitives ----
__device__ __forceinline__ int4 gload16(const void* p) {
  int4 d;
  asm volatile("global_load_dwordx4 %0, %1, off" : "=v"(d) : "v"(p));
  return d;
}
__device__ __forceinline__ int4 gload16_nt(const void* p) {
  int4 d;
  asm volatile("global_load_dwordx4 %0, %1, off nt" : "=v"(d) : "v"(p));
  return d;
}
__device__ __forceinline__ int gload4_nt(const void* p) {
  int d;
  asm volatile("global_load_dword %0, %1, off nt" : "=v"(d) : "v"(p));
  return d;
}
// input operand must be a native ext_vector (i32x4), not HIP's int4 struct
__device__ __forceinline__ void gstore16_nt(void* p, i32x4 v) {
  asm volatile("global_store_dwordx4 %0, %1, off nt" :: "v"(p), "v"(v) : "memory");
}
#define VMW(N) do { asm volatile("s_waitcnt vmcnt(" #N ")" ::: "memory"); \
                    __builtin_amdgcn_sched_barrier(0); } while (0)
#define LGKM_BARRIER() do { \
    asm volatile("s_waitcnt lgkmcnt(0)\n\ts_barrier" ::: "memory"); \
    __builtin_amdgcn_sched_barrier(0); } while (0)

// ---------------------------------------------------------------------------
// Mask storage detector: bool (1 byte/elem) vs int32 (4 bytes/elem).
// ---------------------------------------------------------------------------
__global__ void detect_mask_kernel(const unsigned char* __restrict__ m, int* __restrict__ flag) {
  if (threadIdx.x == 0) {
    int f = 0;
    for (int i = 0; i < 256; ++i)
      if ((i & 3) != 0 && m[i] != 0) f = 1;
    *flag = f;  // 1 => byte mask, 0 => int32 mask
  }
}

// ---------------------------------------------------------------------------
// GEMM v4: 256 thr / 4 waves, 128x128 tile, BK=32, DOUBLE-BUFFERED LDS with
// ONE barrier per K-step (was 2). Order: load(ks+1)->regs, compute(buf[ks&1]),
// store->buf[(ks+1)&1], sync. The store's target was last read at ks-1 (its
// sync protects it); the written buffer is read at ks+1 (after this sync).
// Same K-summation order as v2 -> absmax bit-identical.
// z==2 writes V k-tiled: vt2[bh][k/32][d][k%32].
// ---------------------------------------------------------------------------
__global__ __launch_bounds__(256) void gemm_kernel(
    const float* __restrict__ Aq, const float* __restrict__ Ak, const float* __restrict__ Av,
    const u16* __restrict__ Ao,
    const float* __restrict__ Wq, const float* __restrict__ Wk,
    const float* __restrict__ Wv, const float* __restrict__ Wo,
    const float* __restrict__ bq, const float* __restrict__ bk,
    const float* __restrict__ bv, const float* __restrict__ bo,
    u16* __restrict__ qbuf, u16* __restrict__ kbuf, u16* __restrict__ vTbuf,
    float* __restrict__ outbuf, int mode_base)
{
  const int z = mode_base + (int)blockIdx.z;
  const int n0 = blockIdx.x * 128;
  const int m0 = blockIdx.y * 128;
  const int tid = threadIdx.x;
  const int lane = tid & 63;
  const int wave = tid >> 6;
  const int wm = wave >> 1, wn = wave & 1;

  __shared__ u16 Al[2][128 * 40];
  __shared__ u16 Bl[2][128 * 40];

  const float* Af = (z == 0) ? Aq : (z == 1 ? Ak : Av);
  const float* W  = (z == 0) ? Wq : (z == 1 ? Wk : (z == 2 ? Wv : Wo));

  f32x4 acc[4][4];
#pragma unroll
  for (int i = 0; i < 4; ++i)
#pragma unroll
    for (int j = 0; j < 4; ++j) acc[i][j] = (f32x4){0.f, 0.f, 0.f, 0.f};

  float4 arf[4];
  int4   arb[2];
  float4 brf[4];

  auto load_tiles = [&](int ks) {
    const int kk0 = ks * 32;
    if (z < 3) {
#pragma unroll
      for (int c = 0; c < 4; ++c) {
        int chunk = c * 256 + tid;
        arf[c] = *(const float4*)(Af + (size_t)(m0 + (chunk >> 3)) * DM_ + kk0 + (chunk & 7) * 4);
      }
    } else {
#pragma unroll
      for (int c = 0; c < 2; ++c) {
        int chunk = c * 256 + tid;
        arb[c] = *(const int4*)(Ao + (size_t)(m0 + (chunk >> 2)) * DM_ + kk0 + (chunk & 3) * 8);
      }
    }
#pragma unroll
    for (int c = 0; c < 4; ++c) {
      int chunk = c * 256 + tid;
      brf[c] = *(const float4*)(W + (size_t)(n0 + (chunk >> 3)) * DM_ + kk0 + (chunk & 7) * 4);
    }
  };

  auto store_lds = [&](int buf) {
    u16* Ab = Al[buf];
    u16* Bb = Bl[buf];
    if (z < 3) {
#pragma unroll
      for (int c = 0; c < 4; ++c) {
        int chunk = c * 256 + tid;
        ushort4 p;
        p.x = f2bf(arf[c].x); p.y = f2bf(arf[c].y); p.z = f2bf(arf[c].z); p.w = f2bf(arf[c].w);
        *(ushort4*)(Ab + (chunk >> 3) * 40 + (chunk & 7) * 4) = p;
      }
    } else {
#pragma unroll
      for (int c = 0; c < 2; ++c) {
        int chunk = c * 256 + tid;
        *(int4*)(Ab + (chunk >> 2) * 40 + (chunk & 3) * 8) = arb[c];
      }
    }
#pragma unroll
    for (int c = 0; c < 4; ++c) {
      int chunk = c * 256 + tid;
      ushort4 p;
      p.x = f2bf(brf[c].x); p.y = f2bf(brf[c].y); p.z = f2bf(brf[c].z); p.w = f2bf(brf[c].w);
      *(ushort4*)(Bb + (chunk >> 3) * 40 + (chunk & 7) * 4) = p;
    }
  };

  load_tiles(0);
  store_lds(0);
  __syncthreads();

  for (int ks = 0; ks < 32; ++ks) {
    const int cur = ks & 1;
    if (ks < 31) load_tiles(ks + 1);   // global -> regs (hidden under compute)
    const u16* Ab = Al[cur];
    const u16* Bb = Bl[cur];
    short8 afr[4], bfr[4];
#pragma unroll
    for (int i = 0; i < 4; ++i) {
      afr[i] = ld_short8(Ab + (wm * 64 + i * 16 + (lane & 15)) * 40 + (lane >> 4) * 8);
      bfr[i] = ld_short8(Bb + (wn * 64 + i * 16 + (lane & 15)) * 40 + (lane >> 4) * 8);
    }
#pragma unroll
    for (int i = 0; i < 4; ++i)
#pragma unroll
      for (int j = 0; j < 4; ++j)
        acc[i][j] = __builtin_amdgcn_mfma_f32_16x16x32_bf16(afr[i], bfr[j], acc[i][j], 0, 0, 0);
    if (ks < 31) store_lds(cur ^ 1);   // write next buffer (its readers synced at ks-1)
    __syncthreads();                   // single barrier per K-step
  }

  const float* bias = (z == 0) ? bq : (z == 1 ? bk : (z == 2 ? bv : bo));
#pragma unroll
  for (int i = 0; i < 4; ++i) {
    const int token0 = m0 + wm * 64 + i * 16 + (lane >> 4) * 4;
#pragma unroll
    for (int j = 0; j < 4; ++j) {
      const int feat = n0 + wn * 64 + j * 16 + (lane & 15);
      const float bvl = bias[feat];
      if (z == 3) {
#pragma unroll
        for (int r = 0; r < 4; ++r)
          outbuf[(size_t)(token0 + r) * DM_ + feat] = acc[i][j][r] + bvl;
      } else if (z == 2) {
        // V k-tiled: vt2[bh][k/32][d][k%32]
        const int bb = token0 >> 10, t = token0 & 1023;
        const int hh = feat >> 6, d = feat & 63;
        const int kt = t >> 5, kk = t & 31;
        ushort4 p;
        p.x = f2bf(acc[i][j][0] + bvl);
        p.y = f2bf(acc[i][j][1] + bvl);
        p.z = f2bf(acc[i][j][2] + bvl);
        p.w = f2bf(acc[i][j][3] + bvl);
        *(ushort4*)(vTbuf + (((size_t)(bb * H_ + hh) * 32 + kt) * 64 + d) * 32 + kk) = p;
      } else {
        u16* dst = (z == 0) ? qbuf : kbuf;
        const int hh = feat >> 6, d = feat & 63;
#pragma unroll
        for (int r = 0; r < 4; ++r) {
          const int token = token0 + r;
          const int bb = token >> 10, t = token & 1023;
          dst[((size_t)(bb * H_ + hh) * NQ_ + t) * DK_ + d] = f2bf(acc[i][j][r] + bvl);
        }
      }
    }
  }
}

// ---------------------------------------------------------------------------
// Attention v11 (R14, byte-identical): nt on stream traffic, contiguous
// per-instruction access, cross-phase prefetch, counted vmcnt.
// ---------------------------------------------------------------------------
__global__ __launch_bounds__(512) void attn_kernel(
    const u16* __restrict__ qbuf, const u16* __restrict__ kbuf, const u16* __restrict__ vTbuf,
    const float* __restrict__ aw, const void* __restrict__ maskp, const int* __restrict__ flagp,
    float* __restrict__ attout, u16* __restrict__ obuf)
{
  __shared__ u16 S[16 * 1024];  // 32 KB bf16 strip, col swizzle: c ^ ((row&7)<<3)

  const int n = blockIdx.x;
  const int work = (n & 7) * 512 + (n >> 3);  // XCD-chunked swizzle (perf only)
  const int qt = work & 63;
  const int bh = work >> 6;
  const int b = bh >> 4, h = bh & 15;
  const int qbase = qt * 16;
  const int tid = threadIdx.x;
  const int lane = tid & 63;
  const int wave = tid >> 6;   // 0..7
  const int hi = lane >> 4;
  const int l15 = lane & 15;
  const int l4 = lane * 4;
  const int mflag = *flagp;

  const size_t ab0 = ((size_t)bh * NQ_ + qbase + wave) * (size_t)NK_;
  const size_t ab1 = ab0 + 8 * (size_t)NK_;

  // ---- pre-QK issue: Q(2), K(16), aw row0(4) -- FIFO order is the contract
  const u16* qp = qbuf + ((size_t)bh * NQ_ + qbase + l15) * DK_ + hi * 8;
  int4 qd0 = gload16(qp);
  int4 qd1 = gload16(qp + 32);

  const u16* kbase = kbuf + (size_t)bh * NK_ * DK_;
  const int tkc = wave * 16 + l15;
  int4 kq0[8], kq1[8];
#pragma unroll
  for (int t = 0; t < 8; ++t) {
    const u16* kp_ = kbase + (size_t)(t * 128 + tkc) * DK_ + hi * 8;
    kq0[t] = gload16(kp_);
    kq1[t] = gload16(kp_ + 32);
  }
  int4 aw0[4];
#pragma unroll
  for (int j = 0; j < 4; ++j) aw0[j] = gload16_nt(aw + ab0 + l4 + j * 256);
  // outstanding: 22.  oldest->newest: Q(2), K(16), awR0(4)

  VMW(20);  // Q ready
  const short8 qf0 = __builtin_bit_cast(short8, qd0);
  const short8 qf1 = __builtin_bit_cast(short8, qd1);

#define QK_EAT(t) do { \
    f32x4 sacc_ = (f32x4){0.f, 0.f, 0.f, 0.f}; \
    sacc_ = __builtin_amdgcn_mfma_f32_16x16x32_bf16(qf0, __builtin_bit_cast(short8, kq0[t]), sacc_, 0, 0, 0); \
    sacc_ = __builtin_amdgcn_mfma_f32_16x16x32_bf16(qf1, __builtin_bit_cast(short8, kq1[t]), sacc_, 0, 0, 0); \
    const int tk_ = (t) * 128 + tkc; \
    _Pragma("unroll") \
    for (int r = 0; r < 4; ++r) { \
      const int row_ = hi * 4 + r; \
      S[row_ * 1024 + (tk_ ^ ((row_ & 7) << 3))] = f2bf(sacc_[r]); \
    } } while (0)

  VMW(16);  QK_EAT(0); QK_EAT(1);
  VMW(12);  QK_EAT(2); QK_EAT(3);
  VMW(8);   QK_EAT(4); QK_EAT(5);
  VMW(4);   QK_EAT(6); QK_EAT(7);   // awR0(4) still in flight
#undef QK_EAT

  LGKM_BARRIER();   // S strip visible; aw loads NOT drained

  // ---- softmax (no max-sub): rows wave, wave+8; contiguous NT access ----
  {
    const float scale = 0.125f;

#define SM_BODY(row_, AWV_, KV_, ab_) do { \
    u16* Srow_ = S + (row_) * 1024; \
    const int swz_ = ((row_) & 7) << 3; \
    f32x4 e_[4]; float sum_ = 0.f; \
    _Pragma("unroll") \
    for (int j = 0; j < 4; ++j) { \
      const int c_ = l4 + j * 256; \
      const ushort4 s4_ = *(const ushort4*)(Srow_ + (c_ ^ swz_)); \
      const f32x4 a4_ = __builtin_bit_cast(f32x4, AWV_[j]); \
      f32x4 t_; \
      t_[0] = KV_[j].x ? 0.f : __expf(bf2f(s4_.x) * scale * a4_[0]); \
      t_[1] = KV_[j].y ? 0.f : __expf(bf2f(s4_.y) * scale * a4_[1]); \
      t_[2] = KV_[j].z ? 0.f : __expf(bf2f(s4_.z) * scale * a4_[2]); \
      t_[3] = KV_[j].w ? 0.f : __expf(bf2f(s4_.w) * scale * a4_[3]); \
      e_[j] = t_; \
      sum_ += (t_[0] + t_[1]) + (t_[2] + t_[3]); \
    } \
    _Pragma("unroll") \
    for (int o_ = 32; o_ >= 1; o_ >>= 1) sum_ += __shfl_xor(sum_, o_); \
    const float inv_ = 1.0f / sum_; \
    _Pragma("unroll") \
    for (int j = 0; j < 4; ++j) { \
      const int c_ = l4 + j * 256; \
      f32x4 t_ = e_[j]; \
      t_[0] *= inv_; t_[1] *= inv_; t_[2] *= inv_; t_[3] *= inv_; \
      gstore16_nt((void*)(attout + (ab_) + c_), __builtin_bit_cast(i32x4, t_)); \
      ushort4 p_; \
      p_.x = f2bf(t_[0]); p_.y = f2bf(t_[1]); p_.z = f2bf(t_[2]); p_.w = f2bf(t_[3]); \
      *(ushort4*)(Srow_ + (c_ ^ swz_)) = p_; \
    } \
  } while (0)

    if (mflag) {
      const unsigned char* mp = (const unsigned char*)maskp;
      int mb0[4], mb1[4];
      int4 aw1[4];
#pragma unroll
      for (int j = 0; j < 4; ++j) mb0[j] = gload4_nt(mp + ab0 + l4 + j * 256);
#pragma unroll
      for (int j = 0; j < 4; ++j) aw1[j] = gload16_nt(aw + ab1 + l4 + j * 256);
#pragma unroll
      for (int j = 0; j < 4; ++j) mb1[j] = gload4_nt(mp + ab1 + l4 + j * 256);
      VMW(8);  // awR0 + maskR0 ready; row1's 8 in flight
      int4 k0[4], k1[4];
#pragma unroll
      for (int j = 0; j < 4; ++j) {
        k0[j].x = mb0[j] & 0xff;          k0[j].y = (mb0[j] >> 8) & 0xff;
        k0[j].z = (mb0[j] >> 16) & 0xff;  k0[j].w = (mb0[j] >> 24) & 0xff;
      }
      SM_BODY(wave, aw0, k0, ab0);
      VMW(4);  // awR1 + maskR1 ready; row0's 4 nt-stores are the newest 4
#pragma unroll
      for (int j = 0; j < 4; ++j) {
        k1[j].x = mb1[j] & 0xff;          k1[j].y = (mb1[j] >> 8) & 0xff;
        k1[j].z = (mb1[j] >> 16) & 0xff;  k1[j].w = (mb1[j] >> 24) & 0xff;
      }
      SM_BODY(wave + 8, aw1, k1, ab1);
    } else {
      const int* mp = (const int*)maskp;
      int4 k0[4], aw1[4], k1[4];
#pragma unroll
      for (int j = 0; j < 4; ++j) k0[j] = gload16_nt(mp + ab0 + l4 + j * 256);
#pragma unroll
      for (int j = 0; j < 4; ++j) aw1[j] = gload16_nt(aw + ab1 + l4 + j * 256);
#pragma unroll
      for (int j = 0; j < 4; ++j) k1[j] = gload16_nt(mp + ab1 + l4 + j * 256);
      VMW(8);  // awR0 + maskR0 ready
      SM_BODY(wave, aw0, k0, ab0);
      VMW(4);  // row1 loads ready; row0 nt-stores remain
      SM_BODY(wave + 8, aw1, k1, ab1);
    }
#undef SM_BODY
  }

  LGKM_BARRIER();  // P strip visible for PV; attout stores still in flight
  VMW(0);          // clean FIFO before PV's counted pipeline

  // ---- PV: 2-way k-split, k-tiled V (contiguous loads), dual accumulators
  {
    const int kh = wave >> 2;
    const int j = wave & 3;
    const u16* Sr = S + l15 * 1024;
    const int asw = (l15 & 7) << 3;
    const int dcol = j * 16 + l15;
    const u16* vb2 = vTbuf + (size_t)bh * (NK_ * DK_);
    const int kh512 = kh * 512;
    f32x4 o0 = (f32x4){0.f, 0.f, 0.f, 0.f};
    f32x4 o1 = (f32x4){0.f, 0.f, 0.f, 0.f};
    int4 vq[16];

#define PV_ISSUE(t) do { \
    vq[t] = gload16(vb2 + ((size_t)(kh * 16 + (t)) * 64 + dcol) * 32 + hi * 8); } while (0)
#define PV_EAT(t) do { \
    const int c_ = kh512 + (t) * 32 + hi * 8; \
    const short8 pa_ = ld_short8(Sr + (c_ ^ asw)); \
    if ((t) & 1) o1 = __builtin_amdgcn_mfma_f32_16x16x32_bf16(pa_, __builtin_bit_cast(short8, vq[t]), o1, 0, 0, 0); \
    else        o0 = __builtin_amdgcn_mfma_f32_16x16x32_bf16(pa_, __builtin_bit_cast(short8, vq[t]), o0, 0, 0, 0); \
  } while (0)

    PV_ISSUE(0); PV_ISSUE(1); PV_ISSUE(2); PV_ISSUE(3);
    PV_ISSUE(4); PV_ISSUE(5); PV_ISSUE(6); PV_ISSUE(7);
    VMW(4);
    PV_EAT(0); PV_EAT(1); PV_EAT(2); PV_EAT(3);
    PV_ISSUE(8); PV_ISSUE(9); PV_ISSUE(10); PV_ISSUE(11);
    VMW(4);
    PV_EAT(4); PV_EAT(5); PV_EAT(6); PV_EAT(7);
    PV_ISSUE(12); PV_ISSUE(13); PV_ISSUE(14); PV_ISSUE(15);
    VMW(4);
    PV_EAT(8); PV_EAT(9); PV_EAT(10); PV_EAT(11);
    VMW(0);
    PV_EAT(12); PV_EAT(13); PV_EAT(14); PV_EAT(15);
#undef PV_ISSUE
#undef PV_EAT

    f32x4 oacc = o0 + o1;
    __syncthreads();                 // all P strip reads complete
    float* Pbuf = (float*)S;         // 16 x 64 fp32 partials (4 KB, aliases S)
    if (kh == 1) {
#pragma unroll
      for (int r = 0; r < 4; ++r)
        Pbuf[(hi * 4 + r) * 64 + dcol] = oacc[r];
    }
    __syncthreads();
    if (kh == 0) {
      const int feat = h * DK_ + dcol;
#pragma unroll
      for (int r = 0; r < 4; ++r) {
        const int row = hi * 4 + r;
        obuf[((size_t)b * NQ_ + qbase + row) * DM_ + feat] =
            f2bf(oacc[r] + Pbuf[row * 64 + dcol]);
      }
    }
  }
}

// ---------------------------------------------------------------------------
extern "C" void kernel_launch(void* const* d_in, const int* in_sizes, int n_in,
                              void* d_out, int out_size, void* d_ws, size_t ws_size,
                              hipStream_t stream)
{
  const float* queries = (const float*)d_in[0];
  const float* keys    = (const float*)d_in[1];
  const float* values  = (const float*)d_in[2];
  const float* aw      = (const float*)d_in[3];
  const void*  maskp   = d_in[4];
  const float* Wq = (const float*)d_in[5];
  const float* bq = (const float*)d_in[6];
  const float* Wk = (const float*)d_in[7];
  const float* bk = (const float*)d_in[8];
  const float* Wv = (const float*)d_in[9];
  const float* bv = (const float*)d_in[10];
  const float* Wo = (const float*)d_in[11];
  const float* bo = (const float*)d_in[12];

  char* ws = (char*)d_ws;
  const size_t NE = (size_t)B_ * H_ * NQ_ * DK_;
  int* flag  = (int*)ws;
  u16* qbuf  = (u16*)(ws + 256);
  u16* kbuf  = qbuf + NE;
  u16* vTbuf = kbuf + NE;
  u16* obuf  = vTbuf + NE;
  if (ws_size < 256 + 8 * NE) return;

  float* outp = (float*)d_out;
  float* attp = outp + (size_t)B_ * NQ_ * DM_;

  detect_mask_kernel<<<1, 64, 0, stream>>>((const unsigned char*)maskp, flag);

  gemm_kernel<<<dim3(8, 32, 3), 256, 0, stream>>>(queries, keys, values, obuf,
      Wq, Wk, Wv, Wo, bq, bk, bv, bo, qbuf, kbuf, vTbuf, outp, 0);

  attn_kernel<<<dim3(4096), 512, 0, stream>>>(qbuf, kbuf, vTbuf, aw, maskp, flag,
                                              attp, obuf);

  gemm_kernel<<<dim3(8, 32, 1), 256, 0, stream>>>(queries, keys, values, obuf,
      Wq, Wk, Wv, Wo, bq, bk, bv, bo, qbuf, kbuf, vTbuf, outp, 3);
}